// Round 5
// baseline (6267.893 us; speedup 1.0000x reference)
//
#include <hip/hip_runtime.h>
#include <hip/hip_bf16.h>
#include <math.h>

#define NN   100000
#define FIN  512
#define HH   256
#define FOUT 64

typedef __attribute__((ext_vector_type(8))) short s16x8;
typedef __attribute__((ext_vector_type(4))) float f32x4;

// ---------------- CSR build ----------------
__global__ void k_count(const int* __restrict__ dst, int* __restrict__ cnt, int E) {
    int i = blockIdx.x * 256 + threadIdx.x;
    if (i < E) atomicAdd(&cnt[dst[i]], 1);
}

__global__ void k_block_sums(const int* __restrict__ cnt, int* __restrict__ partial, int n) {
    __shared__ int red[256];
    int base = blockIdx.x * 1024;
    int t = threadIdx.x;
    int s = 0;
#pragma unroll
    for (int i = 0; i < 4; i++) { int idx = base + t * 4 + i; if (idx < n) s += cnt[idx]; }
    red[t] = s; __syncthreads();
    for (int off = 128; off > 0; off >>= 1) {
        if (t < off) red[t] += red[t + off];
        __syncthreads();
    }
    if (t == 0) partial[blockIdx.x] = red[0];
}

__global__ void k_scan_partials(int* partial, int nb, int* row_ptr, int n) {
    if (threadIdx.x == 0) {
        int run = 0;
        for (int i = 0; i < nb; i++) { int v = partial[i]; partial[i] = run; run += v; }
        row_ptr[n] = run;
    }
}

__global__ void k_write_rowptr(const int* __restrict__ cnt, const int* __restrict__ partial,
                               int* __restrict__ row_ptr, int* __restrict__ cur, int n) {
    __shared__ int sc[256];
    int base = blockIdx.x * 1024;
    int t = threadIdx.x;
    int v[4]; int s = 0;
#pragma unroll
    for (int i = 0; i < 4; i++) { int idx = base + t * 4 + i; v[i] = (idx < n) ? cnt[idx] : 0; s += v[i]; }
    sc[t] = s; __syncthreads();
    for (int off = 1; off < 256; off <<= 1) {
        int add = (t >= off) ? sc[t - off] : 0;
        __syncthreads();
        sc[t] += add;
        __syncthreads();
    }
    int run = partial[blockIdx.x] + sc[t] - s;
#pragma unroll
    for (int i = 0; i < 4; i++) {
        int idx = base + t * 4 + i;
        if (idx < n) { row_ptr[idx] = run; cur[idx] = run; run += v[i]; }
    }
}

__global__ void k_dinv(const int* __restrict__ cnt, float* __restrict__ dinv, int n) {
    int i = blockIdx.x * 256 + threadIdx.x;
    if (i < n) dinv[i] = 1.0f / sqrtf((float)(cnt[i] + 1));
}

__global__ void k_scatter(const int* __restrict__ src, const int* __restrict__ dst,
                          const float* __restrict__ dinv, int* __restrict__ cur,
                          int* __restrict__ src_sorted, float* __restrict__ norm_sorted, int E) {
    int i = blockIdx.x * 256 + threadIdx.x;
    if (i < E) {
        int s = src[i], d = dst[i];
        int p = atomicAdd(&cur[d], 1);
        src_sorted[p] = s;
        norm_sorted[p] = dinv[s] * dinv[d];
    }
}

// ---------------- bf16 split helpers ----------------
__device__ __forceinline__ short f2bf_rn(float f) {
    unsigned b = __float_as_uint(f);
    unsigned r = b + 0x7FFFu + ((b >> 16) & 1u);
    return (short)(r >> 16);
}
__device__ __forceinline__ float bf2f(short h) {
    return __uint_as_float(((unsigned)(unsigned short)h) << 16);
}
__device__ __forceinline__ void split_bf16(float f, short& hi, short& lo) {
    hi = f2bf_rn(f);
    lo = f2bf_rn(f - bf2f(hi));
}

// ---------------- weight prep: fp32 [K][256] -> fragment-chunk bf16 hi/lo ----------------
__global__ void k_wprep(const float* __restrict__ W, short* __restrict__ whi,
                        short* __restrict__ wlo, int K) {
    int t = blockIdx.x * 256 + threadIdx.x;
    int total = K * HH / 8;
    if (t >= total) return;
    int colin = t & 15, g = (t >> 4) & 3, nt = (t >> 6) & 15, kt = t >> 10;
    int col = nt * 16 + colin, kb = kt * 32 + g * 8;
    s16x8 h8, l8;
#pragma unroll
    for (int j = 0; j < 8; j++) {
        float f = W[(size_t)(kb + j) * HH + col];
        short h, l; split_bf16(f, h, l);
        h8[j] = h; l8[j] = l;
    }
    *(s16x8*)&whi[(size_t)t * 8] = h8;
    *(s16x8*)&wlo[(size_t)t * 8] = l8;
}

// ---------------- split-bf16 MFMA GEMM: C[M,256] = A[M,K] @ W[K,256] + epilogue ----------------
// MODE 0: C = relu(AW + bias) ; MODE 1: C = relu((1-beta)*Z + beta*AW)
// A-staging and Z reads are non-temporal (streaming); weights stay cached.
template <int K, int MODE>
__global__ __launch_bounds__(256) void k_mgemm(
    const float* __restrict__ A, const short* __restrict__ Whi, const short* __restrict__ Wlo,
    const float* __restrict__ bias, const float* __restrict__ Z,
    float* __restrict__ C, int M, float beta) {
    __shared__ short As_hi[2048];
    __shared__ short As_lo[2048];
    int tid = threadIdx.x;
    int lane = tid & 63, wid = tid >> 6;
    int wm = wid >> 1, wn = wid & 1;
    int bm = blockIdx.y * 64, bn = blockIdx.x * 64;

    int st_row = tid >> 2, st_g = tid & 3;
    int st_cphys = ((st_row & 15) ^ ((st_g & 1) << 2)) + 16 * st_g + 64 * (st_row >> 4);
    const float* st_ap = A + (size_t)(bm + st_row) * K + st_g * 8;
    bool st_ok = (bm + st_row) < M;

    int fr_g = lane >> 4, fr_r = lane & 15;
    int fr_base = (fr_r ^ ((fr_g & 1) << 2)) + 16 * fr_g;
    int c0 = (fr_base + 64 * (wm * 2 + 0)) * 8;
    int c1 = (fr_base + 64 * (wm * 2 + 1)) * 8;

    int lane_off = fr_g * 16 + fr_r;
    int ntbase = (bn >> 4) + wn * 2;

    f32x4 acc[2][2] = {};

    for (int k0 = 0; k0 < K; k0 += 32) {
        f32x4 v0 = {0.f, 0.f, 0.f, 0.f}, v1 = {0.f, 0.f, 0.f, 0.f};
        if (st_ok) {
            v0 = __builtin_nontemporal_load((const f32x4*)(st_ap + k0));
            v1 = __builtin_nontemporal_load((const f32x4*)(st_ap + k0 + 4));
        }
        s16x8 h8, l8;
        {
            float f[8] = {v0.x, v0.y, v0.z, v0.w, v1.x, v1.y, v1.z, v1.w};
#pragma unroll
            for (int j = 0; j < 8; j++) { short h, l; split_bf16(f[j], h, l); h8[j] = h; l8[j] = l; }
        }
        *(s16x8*)&As_hi[st_cphys * 8] = h8;
        *(s16x8*)&As_lo[st_cphys * 8] = l8;
        __syncthreads();

        int kt = k0 >> 5;
        size_t btile = (size_t)kt * 1024 + (size_t)ntbase * 64;
        s16x8 bh0 = *(const s16x8*)&Whi[(btile + lane_off) * 8];
        s16x8 bl0 = *(const s16x8*)&Wlo[(btile + lane_off) * 8];
        s16x8 bh1 = *(const s16x8*)&Whi[(btile + 64 + lane_off) * 8];
        s16x8 bl1 = *(const s16x8*)&Wlo[(btile + 64 + lane_off) * 8];

        s16x8 ah0 = *(const s16x8*)&As_hi[c0];
        s16x8 al0 = *(const s16x8*)&As_lo[c0];
        s16x8 ah1 = *(const s16x8*)&As_hi[c1];
        s16x8 al1 = *(const s16x8*)&As_lo[c1];

        acc[0][0] = __builtin_amdgcn_mfma_f32_16x16x32_bf16(ah0, bh0, acc[0][0], 0, 0, 0);
        acc[0][1] = __builtin_amdgcn_mfma_f32_16x16x32_bf16(ah0, bh1, acc[0][1], 0, 0, 0);
        acc[1][0] = __builtin_amdgcn_mfma_f32_16x16x32_bf16(ah1, bh0, acc[1][0], 0, 0, 0);
        acc[1][1] = __builtin_amdgcn_mfma_f32_16x16x32_bf16(ah1, bh1, acc[1][1], 0, 0, 0);
        acc[0][0] = __builtin_amdgcn_mfma_f32_16x16x32_bf16(ah0, bl0, acc[0][0], 0, 0, 0);
        acc[0][1] = __builtin_amdgcn_mfma_f32_16x16x32_bf16(ah0, bl1, acc[0][1], 0, 0, 0);
        acc[1][0] = __builtin_amdgcn_mfma_f32_16x16x32_bf16(ah1, bl0, acc[1][0], 0, 0, 0);
        acc[1][1] = __builtin_amdgcn_mfma_f32_16x16x32_bf16(ah1, bl1, acc[1][1], 0, 0, 0);
        acc[0][0] = __builtin_amdgcn_mfma_f32_16x16x32_bf16(al0, bh0, acc[0][0], 0, 0, 0);
        acc[0][1] = __builtin_amdgcn_mfma_f32_16x16x32_bf16(al0, bh1, acc[0][1], 0, 0, 0);
        acc[1][0] = __builtin_amdgcn_mfma_f32_16x16x32_bf16(al1, bh0, acc[1][0], 0, 0, 0);
        acc[1][1] = __builtin_amdgcn_mfma_f32_16x16x32_bf16(al1, bh1, acc[1][1], 0, 0, 0);
        __syncthreads();
    }

    int rsub = (lane >> 4) * 4, csub = lane & 15;
#pragma unroll
    for (int rt = 0; rt < 2; rt++) {
#pragma unroll
        for (int ct = 0; ct < 2; ct++) {
            int col = bn + wn * 32 + ct * 16 + csub;
            int r0 = bm + wm * 32 + rt * 16 + rsub;
#pragma unroll
            for (int reg = 0; reg < 4; reg++) {
                int row = r0 + reg;
                if (row < M) {
                    size_t idx = (size_t)row * HH + col;
                    float a = acc[rt][ct][reg];
                    float o;
                    if (MODE == 0) o = fmaxf(a + bias[col], 0.f);
                    else {
                        float z = __builtin_nontemporal_load(&Z[idx]);
                        o = fmaxf((1.f - beta) * z + beta * a, 0.f);
                    }
                    C[idx] = o;  // regular store: keep fresh h resident in L3 for gathers
                }
            }
        }
    }
}

// ---------------- SpMM propagate + residual: z = 0.9*Ahat@h + 0.1*x0 ----------------
// h gathers + x0 regular (want L3-resident); z writes non-temporal (streaming).
__global__ __launch_bounds__(256) void k_propagate(
    const float* __restrict__ h, const float* __restrict__ x0,
    const int* __restrict__ row_ptr, const int* __restrict__ src_sorted,
    const float* __restrict__ norm_sorted, const float* __restrict__ dinv,
    float* __restrict__ z_out) {
    int wv = threadIdx.x >> 6, lane = threadIdx.x & 63;
    int node = blockIdx.x * 4 + wv;
    if (node >= NN) return;
    int f = lane * 4;
    size_t base = (size_t)node * HH + f;
    float di = dinv[node];
    float sw = di * di;
    f32x4 acc = *(const f32x4*)&h[base];
    acc *= sw;
    int e = __builtin_amdgcn_readfirstlane(row_ptr[node]);
    int end = __builtin_amdgcn_readfirstlane(row_ptr[node + 1]);
    // 8-deep unroll: 8 outstanding 1KB row-gathers per wave
    for (; e + 7 < end; e += 8) {
        int s[8]; float w[8];
#pragma unroll
        for (int j = 0; j < 8; j++) { s[j] = src_sorted[e + j]; w[j] = norm_sorted[e + j]; }
        f32x4 v[8];
#pragma unroll
        for (int j = 0; j < 8; j++) v[j] = *(const f32x4*)&h[(size_t)s[j] * HH + f];
#pragma unroll
        for (int j = 0; j < 8; j++) acc += w[j] * v[j];
    }
    for (; e < end; e++) {
        int s0 = src_sorted[e];
        float w0 = norm_sorted[e];
        acc += w0 * (*(const f32x4*)&h[(size_t)s0 * HH + f]);
    }
    f32x4 xv = *(const f32x4*)&x0[base];
    f32x4 z = 0.9f * acc + 0.1f * xv;
    __builtin_nontemporal_store(z, (f32x4*)&z_out[base]);
}

// ---------------- final: logits/softmax/argmax ----------------
__global__ __launch_bounds__(256) void k_final(
    const float* __restrict__ h, const float* __restrict__ Wc, const float* __restrict__ bc,
    float* __restrict__ logits, float* __restrict__ soft, float* __restrict__ hard) {
    int wv = threadIdx.x >> 6, lane = threadIdx.x & 63;
    int node = blockIdx.x * 4 + wv;
    if (node >= NN) return;
    const float* hr = &h[(size_t)node * HH];
    float acc = bc[lane];
    for (int k = 0; k < HH; k += 4) {
        f32x4 hv = __builtin_nontemporal_load((const f32x4*)&hr[k]);
        acc += hv.x * Wc[(k + 0) * FOUT + lane];
        acc += hv.y * Wc[(k + 1) * FOUT + lane];
        acc += hv.z * Wc[(k + 2) * FOUT + lane];
        acc += hv.w * Wc[(k + 3) * FOUT + lane];
    }
    float m = acc;
    for (int off = 32; off > 0; off >>= 1) m = fmaxf(m, __shfl_xor(m, off));
    float ev = expf(acc - m);
    float s = ev;
    for (int off = 32; off > 0; off >>= 1) s += __shfl_xor(s, off);
    float sm = ev / s;
    int idx = lane; float v = acc;
    for (int off = 1; off < 64; off <<= 1) {
        float ov = __shfl_xor(v, off);
        int oi = __shfl_xor(idx, off);
        if (ov > v || (ov == v && oi < idx)) { v = ov; idx = oi; }
    }
    logits[(size_t)node * FOUT + lane] = acc;
    soft[(size_t)node * FOUT + lane] = sm;
    if (lane == 0) hard[node] = (float)idx;
}

extern "C" void kernel_launch(void* const* d_in, const int* in_sizes, int n_in,
                              void* d_out, int out_size, void* d_ws, size_t ws_size,
                              hipStream_t stream) {
    const float* x  = (const float*)d_in[0];
    const int*   ei = (const int*)d_in[1];
    const float* W0 = (const float*)d_in[2];
    const float* b0 = (const float*)d_in[3];
    const float* Ws = (const float*)d_in[4];
    const float* Wc = (const float*)d_in[5];
    const float* bc = (const float*)d_in[6];
    const int E = in_sizes[1] / 2;
    const int N = in_sizes[0] / FIN;
    const int L = in_sizes[4] / (HH * HH);

    float* out    = (float*)d_out;
    float* logits = out;
    float* emb    = out + (size_t)N * FOUT;   // [N,256] — also the fp32 h ping buffer
    float* soft   = emb + (size_t)N * HH;
    float* hard   = soft + (size_t)N * FOUT;

    char* p = (char*)d_ws;
    size_t off = 0;
    auto alloc = [&](size_t bytes) { void* r = p + off; off += (bytes + 255) & ~(size_t)255; return r; };
    int*   cnt         = (int*)alloc((size_t)N * 4);
    int*   row_ptr     = (int*)alloc((size_t)(N + 1) * 4);
    int*   cur         = (int*)alloc((size_t)N * 4);
    int*   partial     = (int*)alloc(4096 * 4);
    float* dinv        = (float*)alloc((size_t)N * 4);
    int*   src_sorted  = (int*)alloc((size_t)E * 4);
    float* norm_sorted = (float*)alloc((size_t)E * 4);
    float* X0          = (float*)alloc((size_t)N * HH * 4);
    float* A           = (float*)alloc((size_t)N * HH * 4);
    short* W0hi        = (short*)alloc((size_t)FIN * HH * 2);
    short* W0lo        = (short*)alloc((size_t)FIN * HH * 2);
    short* Wshi        = (short*)alloc((size_t)L * HH * HH * 2);
    short* Wslo        = (short*)alloc((size_t)L * HH * HH * 2);

    const int* srcp = ei;
    const int* dstp = ei + E;

    hipMemsetAsync(cnt, 0, (size_t)N * 4, stream);
    k_count<<<(E + 255) / 256, 256, 0, stream>>>(dstp, cnt, E);
    const int nb = (N + 1023) / 1024;
    k_block_sums<<<nb, 256, 0, stream>>>(cnt, partial, N);
    k_scan_partials<<<1, 64, 0, stream>>>(partial, nb, row_ptr, N);
    k_write_rowptr<<<nb, 256, 0, stream>>>(cnt, partial, row_ptr, cur, N);
    k_dinv<<<(N + 255) / 256, 256, 0, stream>>>(cnt, dinv, N);
    k_scatter<<<(E + 255) / 256, 256, 0, stream>>>(srcp, dstp, dinv, cur, src_sorted, norm_sorted, E);

    k_wprep<<<(FIN * HH / 8 + 255) / 256, 256, 0, stream>>>(W0, W0hi, W0lo, FIN);
    for (int i = 0; i < L; i++)
        k_wprep<<<(HH * HH / 8 + 255) / 256, 256, 0, stream>>>(
            Ws + (size_t)i * HH * HH, Wshi + (size_t)i * HH * HH, Wslo + (size_t)i * HH * HH, HH);

    dim3 gg(HH / 64, (N + 63) / 64);
    k_mgemm<FIN, 0><<<gg, 256, 0, stream>>>(x, W0hi, W0lo, b0, nullptr, X0, N, 0.f);

    const float* h = X0;
    for (int i = 0; i < L; i++) {
        float beta = (float)log(0.5 / (i + 1) + 1.0);
        k_propagate<<<(N + 3) / 4, 256, 0, stream>>>(h, X0, row_ptr, src_sorted, norm_sorted, dinv, A);
        k_mgemm<HH, 1><<<gg, 256, 0, stream>>>(A, Wshi + (size_t)i * HH * HH, Wslo + (size_t)i * HH * HH,
                                               nullptr, A, emb, N, beta);
        h = emb;
    }
    k_final<<<(N + 3) / 4, 256, 0, stream>>>(emb, Wc, bc, logits, soft, hard);
}

// Round 6
// 5659.880 us; speedup vs baseline: 1.1074x; 1.1074x over previous
//
#include <hip/hip_runtime.h>
#include <hip/hip_bf16.h>
#include <math.h>

#define NN   100000
#define FIN  512
#define HH   256
#define FOUT 64

typedef __attribute__((ext_vector_type(8))) short s16x8;
typedef __attribute__((ext_vector_type(4))) float f32x4;

// ---------------- CSR build ----------------
__global__ void k_count(const int* __restrict__ dst, int* __restrict__ cnt, int E) {
    int i = blockIdx.x * 256 + threadIdx.x;
    if (i < E) atomicAdd(&cnt[dst[i]], 1);
}

__global__ void k_block_sums(const int* __restrict__ cnt, int* __restrict__ partial, int n) {
    __shared__ int red[256];
    int base = blockIdx.x * 1024;
    int t = threadIdx.x;
    int s = 0;
#pragma unroll
    for (int i = 0; i < 4; i++) { int idx = base + t * 4 + i; if (idx < n) s += cnt[idx]; }
    red[t] = s; __syncthreads();
    for (int off = 128; off > 0; off >>= 1) {
        if (t < off) red[t] += red[t + off];
        __syncthreads();
    }
    if (t == 0) partial[blockIdx.x] = red[0];
}

__global__ void k_scan_partials(int* partial, int nb, int* row_ptr, int n) {
    if (threadIdx.x == 0) {
        int run = 0;
        for (int i = 0; i < nb; i++) { int v = partial[i]; partial[i] = run; run += v; }
        row_ptr[n] = run;
    }
}

__global__ void k_write_rowptr(const int* __restrict__ cnt, const int* __restrict__ partial,
                               int* __restrict__ row_ptr, int* __restrict__ cur, int n) {
    __shared__ int sc[256];
    int base = blockIdx.x * 1024;
    int t = threadIdx.x;
    int v[4]; int s = 0;
#pragma unroll
    for (int i = 0; i < 4; i++) { int idx = base + t * 4 + i; v[i] = (idx < n) ? cnt[idx] : 0; s += v[i]; }
    sc[t] = s; __syncthreads();
    for (int off = 1; off < 256; off <<= 1) {
        int add = (t >= off) ? sc[t - off] : 0;
        __syncthreads();
        sc[t] += add;
        __syncthreads();
    }
    int run = partial[blockIdx.x] + sc[t] - s;
#pragma unroll
    for (int i = 0; i < 4; i++) {
        int idx = base + t * 4 + i;
        if (idx < n) { row_ptr[idx] = run; cur[idx] = run; run += v[i]; }
    }
}

__global__ void k_dinv(const int* __restrict__ cnt, float* __restrict__ dinv, int n) {
    int i = blockIdx.x * 256 + threadIdx.x;
    if (i < n) dinv[i] = 1.0f / sqrtf((float)(cnt[i] + 1));
}

__global__ void k_scatter(const int* __restrict__ src, const int* __restrict__ dst,
                          const float* __restrict__ dinv, int* __restrict__ cur,
                          int* __restrict__ src_sorted, float* __restrict__ norm_sorted, int E) {
    int i = blockIdx.x * 256 + threadIdx.x;
    if (i < E) {
        int s = src[i], d = dst[i];
        int p = atomicAdd(&cur[d], 1);
        src_sorted[p] = s;
        norm_sorted[p] = dinv[s] * dinv[d];
    }
}

// ---------------- bf16 split helpers ----------------
__device__ __forceinline__ short f2bf_rn(float f) {
    unsigned b = __float_as_uint(f);
    unsigned r = b + 0x7FFFu + ((b >> 16) & 1u);
    return (short)(r >> 16);
}
__device__ __forceinline__ float bf2f(short h) {
    return __uint_as_float(((unsigned)(unsigned short)h) << 16);
}
__device__ __forceinline__ void split_bf16(float f, short& hi, short& lo) {
    hi = f2bf_rn(f);
    lo = f2bf_rn(f - bf2f(hi));
}

// ---------------- weight prep: fp32 [K][256] -> fragment-chunk bf16 hi/lo ----------------
// chunk ci = kt*1024 + nt*64 + g*16 + colin ; holds W[kt*32+g*8+j][nt*16+colin], j=0..7
__global__ void k_wprep(const float* __restrict__ W, short* __restrict__ whi,
                        short* __restrict__ wlo, int K) {
    int t = blockIdx.x * 256 + threadIdx.x;
    int total = K * HH / 8;
    if (t >= total) return;
    int colin = t & 15, g = (t >> 4) & 3, nt = (t >> 6) & 15, kt = t >> 10;
    int col = nt * 16 + colin, kb = kt * 32 + g * 8;
    s16x8 h8, l8;
#pragma unroll
    for (int j = 0; j < 8; j++) {
        float f = W[(size_t)(kb + j) * HH + col];
        short h, l; split_bf16(f, h, l);
        h8[j] = h; l8[j] = l;
    }
    *(s16x8*)&whi[(size_t)t * 8] = h8;
    *(s16x8*)&wlo[(size_t)t * 8] = l8;
}

// ---------------- first GEMM: X0 = relu(x@W0 + b0), full-width 64x256 blocks ----------------
__global__ __launch_bounds__(256) void k_gemm0(
    const float* __restrict__ A, const short* __restrict__ Whi, const short* __restrict__ Wlo,
    const float* __restrict__ bias, float* __restrict__ C, int M) {
    __shared__ short As_hi[2048];
    __shared__ short As_lo[2048];
    int tid = threadIdx.x, lane = tid & 63, wid = tid >> 6;
    int wm = wid >> 1, wn = wid & 1;
    int bm = blockIdx.x * 64;
    int st_row = tid >> 2, st_g = tid & 3;
    int st_cphys = ((st_row & 15) ^ ((st_g & 1) << 2)) + 16 * st_g + 64 * (st_row >> 4);
    const float* st_ap = A + (size_t)(bm + st_row) * FIN + st_g * 8;
    bool st_ok = (bm + st_row) < M;
    int fr_g = lane >> 4, fr_r = lane & 15;
    int fr_base = (fr_r ^ ((fr_g & 1) << 2)) + 16 * fr_g;
    int c0 = (fr_base + 64 * (wm * 2 + 0)) * 8;
    int c1 = (fr_base + 64 * (wm * 2 + 1)) * 8;
    int lane_off = fr_g * 16 + fr_r;
    f32x4 acc[2][8] = {};
    for (int kt = 0; kt < FIN / 32; kt++) {
        int k0 = kt * 32;
        f32x4 v0 = {0.f, 0.f, 0.f, 0.f}, v1 = {0.f, 0.f, 0.f, 0.f};
        if (st_ok) { v0 = *(const f32x4*)(st_ap + k0); v1 = *(const f32x4*)(st_ap + k0 + 4); }
        s16x8 h8, l8;
        {
            float fv[8] = {v0.x, v0.y, v0.z, v0.w, v1.x, v1.y, v1.z, v1.w};
#pragma unroll
            for (int j = 0; j < 8; j++) { short hh, ll; split_bf16(fv[j], hh, ll); h8[j] = hh; l8[j] = ll; }
        }
        *(s16x8*)&As_hi[st_cphys * 8] = h8;
        *(s16x8*)&As_lo[st_cphys * 8] = l8;
        __syncthreads();
        s16x8 ah0 = *(const s16x8*)&As_hi[c0], al0 = *(const s16x8*)&As_lo[c0];
        s16x8 ah1 = *(const s16x8*)&As_hi[c1], al1 = *(const s16x8*)&As_lo[c1];
        size_t btile = (size_t)kt * 1024 + (size_t)(wn * 8) * 64;
#pragma unroll
        for (int ct = 0; ct < 8; ct++) {
            s16x8 bh = *(const s16x8*)&Whi[(btile + ct * 64 + lane_off) * 8];
            s16x8 bl = *(const s16x8*)&Wlo[(btile + ct * 64 + lane_off) * 8];
            acc[0][ct] = __builtin_amdgcn_mfma_f32_16x16x32_bf16(ah0, bh, acc[0][ct], 0, 0, 0);
            acc[0][ct] = __builtin_amdgcn_mfma_f32_16x16x32_bf16(al0, bh, acc[0][ct], 0, 0, 0);
            acc[0][ct] = __builtin_amdgcn_mfma_f32_16x16x32_bf16(ah0, bl, acc[0][ct], 0, 0, 0);
            acc[1][ct] = __builtin_amdgcn_mfma_f32_16x16x32_bf16(ah1, bh, acc[1][ct], 0, 0, 0);
            acc[1][ct] = __builtin_amdgcn_mfma_f32_16x16x32_bf16(al1, bh, acc[1][ct], 0, 0, 0);
            acc[1][ct] = __builtin_amdgcn_mfma_f32_16x16x32_bf16(ah1, bl, acc[1][ct], 0, 0, 0);
        }
        __syncthreads();
    }
    int rsub = (lane >> 4) * 4, csub = lane & 15;
#pragma unroll
    for (int rt = 0; rt < 2; rt++)
#pragma unroll
        for (int ct = 0; ct < 8; ct++) {
            int col = wn * 128 + ct * 16 + csub;
            int r0 = bm + wm * 32 + rt * 16 + rsub;
#pragma unroll
            for (int reg = 0; reg < 4; reg++) {
                int row = r0 + reg;
                if (row < M) C[(size_t)row * HH + col] = fmaxf(acc[rt][ct][reg] + bias[col], 0.f);
            }
        }
}

// ---------------- fused layer: gather+residual into LDS, then GEMM + epilogue ----------------
// h_next = relu((1-beta)*z + beta*(z@Ws)), z = 0.9*Ahat@h + 0.1*x0
__global__ __launch_bounds__(256) void k_layer(
    const float* __restrict__ h, const float* __restrict__ x0,
    const int* __restrict__ row_ptr, const int* __restrict__ src_sorted,
    const float* __restrict__ norm_sorted, const float* __restrict__ dinv,
    const short* __restrict__ Whi, const short* __restrict__ Wlo,
    float* __restrict__ C, int M, float beta) {
    __shared__ float zbuf[16384];      // 64 rows x 256 cols fp32, 4-float blocks XOR-swizzled
    __shared__ short As_hi[2048];
    __shared__ short As_lo[2048];
    int tid = threadIdx.x, lane = tid & 63, wid = tid >> 6;
    int bm = blockIdx.x * 64;

    // ---- phase 1: gather 64 z-rows into zbuf ----
    {
        int f = lane * 4;
        for (int r16 = 0; r16 < 16; r16++) {
            int rl = r16 * 4 + wid;
            int node = bm + rl;
            if (node < M) {
                size_t base = (size_t)node * HH + f;
                float di = dinv[node];
                float sw = di * di;
                f32x4 acc = *(const f32x4*)&h[base];
                acc *= sw;
                int e = __builtin_amdgcn_readfirstlane(row_ptr[node]);
                int end = __builtin_amdgcn_readfirstlane(row_ptr[node + 1]);
                for (; e + 3 < end; e += 4) {
                    int s0 = src_sorted[e], s1 = src_sorted[e + 1];
                    int s2 = src_sorted[e + 2], s3 = src_sorted[e + 3];
                    float w0 = norm_sorted[e], w1 = norm_sorted[e + 1];
                    float w2 = norm_sorted[e + 2], w3 = norm_sorted[e + 3];
                    f32x4 v0 = *(const f32x4*)&h[(size_t)s0 * HH + f];
                    f32x4 v1 = *(const f32x4*)&h[(size_t)s1 * HH + f];
                    f32x4 v2 = *(const f32x4*)&h[(size_t)s2 * HH + f];
                    f32x4 v3 = *(const f32x4*)&h[(size_t)s3 * HH + f];
                    acc += w0 * v0 + w1 * v1 + w2 * v2 + w3 * v3;
                }
                for (; e < end; e++) {
                    int s0 = src_sorted[e];
                    float w0 = norm_sorted[e];
                    acc += w0 * (*(const f32x4*)&h[(size_t)s0 * HH + f]);
                }
                f32x4 xv = __builtin_nontemporal_load((const f32x4*)&x0[base]);
                f32x4 z = 0.9f * acc + 0.1f * xv;
                int phys = lane ^ (rl & 7);
                *(f32x4*)&zbuf[rl * 256 + phys * 4] = z;
            }
        }
    }
    __syncthreads();

    // ---- phase 2: GEMM z@Ws from zbuf ----
    int wm = wid >> 1, wn = wid & 1;
    int st_row = tid >> 2, st_g = tid & 3;
    int st_cphys = ((st_row & 15) ^ ((st_g & 1) << 2)) + 16 * st_g + 64 * (st_row >> 4);
    int fr_g = lane >> 4, fr_r = lane & 15;
    int fr_base = (fr_r ^ ((fr_g & 1) << 2)) + 16 * fr_g;
    int c0 = (fr_base + 64 * (wm * 2 + 0)) * 8;
    int c1 = (fr_base + 64 * (wm * 2 + 1)) * 8;
    int lane_off = fr_g * 16 + fr_r;
    int zr = st_row * 256, swz = st_row & 7;
    f32x4 acc[2][8] = {};
    for (int kt = 0; kt < 8; kt++) {
        int b0 = kt * 8 + st_g * 2;
        f32x4 v0 = *(const f32x4*)&zbuf[zr + ((b0 ^ swz) * 4)];
        f32x4 v1 = *(const f32x4*)&zbuf[zr + (((b0 + 1) ^ swz) * 4)];
        s16x8 h8, l8;
        {
            float fv[8] = {v0.x, v0.y, v0.z, v0.w, v1.x, v1.y, v1.z, v1.w};
#pragma unroll
            for (int j = 0; j < 8; j++) { short hh, ll; split_bf16(fv[j], hh, ll); h8[j] = hh; l8[j] = ll; }
        }
        *(s16x8*)&As_hi[st_cphys * 8] = h8;
        *(s16x8*)&As_lo[st_cphys * 8] = l8;
        __syncthreads();
        s16x8 ah0 = *(const s16x8*)&As_hi[c0], al0 = *(const s16x8*)&As_lo[c0];
        s16x8 ah1 = *(const s16x8*)&As_hi[c1], al1 = *(const s16x8*)&As_lo[c1];
        size_t btile = (size_t)kt * 1024 + (size_t)(wn * 8) * 64;
#pragma unroll
        for (int ct = 0; ct < 8; ct++) {
            s16x8 bh = *(const s16x8*)&Whi[(btile + ct * 64 + lane_off) * 8];
            s16x8 bl = *(const s16x8*)&Wlo[(btile + ct * 64 + lane_off) * 8];
            acc[0][ct] = __builtin_amdgcn_mfma_f32_16x16x32_bf16(ah0, bh, acc[0][ct], 0, 0, 0);
            acc[0][ct] = __builtin_amdgcn_mfma_f32_16x16x32_bf16(al0, bh, acc[0][ct], 0, 0, 0);
            acc[0][ct] = __builtin_amdgcn_mfma_f32_16x16x32_bf16(ah0, bl, acc[0][ct], 0, 0, 0);
            acc[1][ct] = __builtin_amdgcn_mfma_f32_16x16x32_bf16(ah1, bh, acc[1][ct], 0, 0, 0);
            acc[1][ct] = __builtin_amdgcn_mfma_f32_16x16x32_bf16(al1, bh, acc[1][ct], 0, 0, 0);
            acc[1][ct] = __builtin_amdgcn_mfma_f32_16x16x32_bf16(ah1, bl, acc[1][ct], 0, 0, 0);
        }
        __syncthreads();
    }

    // ---- epilogue: h_next = relu((1-beta)*z + beta*acc) ----
    int rsub = (lane >> 4) * 4, csub = lane & 15;
    float ob = 1.f - beta;
#pragma unroll
    for (int rt = 0; rt < 2; rt++)
#pragma unroll
        for (int ct = 0; ct < 8; ct++) {
            int col = wn * 128 + ct * 16 + csub;
            int r0 = wm * 32 + rt * 16 + rsub;
#pragma unroll
            for (int reg = 0; reg < 4; reg++) {
                int rl = r0 + reg;
                int row = bm + rl;
                if (row < M) {
                    float z = zbuf[rl * 256 + (((col >> 2) ^ (rl & 7)) * 4) + (col & 3)];
                    C[(size_t)row * HH + col] = fmaxf(ob * z + beta * acc[rt][ct][reg], 0.f);
                }
            }
        }
}

// ---------------- final: logits/softmax/argmax ----------------
__global__ __launch_bounds__(256) void k_final(
    const float* __restrict__ h, const float* __restrict__ Wc, const float* __restrict__ bc,
    float* __restrict__ logits, float* __restrict__ soft, float* __restrict__ hard) {
    int wv = threadIdx.x >> 6, lane = threadIdx.x & 63;
    int node = blockIdx.x * 4 + wv;
    if (node >= NN) return;
    const float* hr = &h[(size_t)node * HH];
    float acc = bc[lane];
    for (int k = 0; k < HH; k += 4) {
        f32x4 hv = *(const f32x4*)&hr[k];
        acc += hv.x * Wc[(k + 0) * FOUT + lane];
        acc += hv.y * Wc[(k + 1) * FOUT + lane];
        acc += hv.z * Wc[(k + 2) * FOUT + lane];
        acc += hv.w * Wc[(k + 3) * FOUT + lane];
    }
    float m = acc;
    for (int off = 32; off > 0; off >>= 1) m = fmaxf(m, __shfl_xor(m, off));
    float ev = expf(acc - m);
    float s = ev;
    for (int off = 32; off > 0; off >>= 1) s += __shfl_xor(s, off);
    float sm = ev / s;
    int idx = lane; float v = acc;
    for (int off = 1; off < 64; off <<= 1) {
        float ov = __shfl_xor(v, off);
        int oi = __shfl_xor(idx, off);
        if (ov > v || (ov == v && oi < idx)) { v = ov; idx = oi; }
    }
    logits[(size_t)node * FOUT + lane] = acc;
    soft[(size_t)node * FOUT + lane] = sm;
    if (lane == 0) hard[node] = (float)idx;
}

extern "C" void kernel_launch(void* const* d_in, const int* in_sizes, int n_in,
                              void* d_out, int out_size, void* d_ws, size_t ws_size,
                              hipStream_t stream) {
    const float* x  = (const float*)d_in[0];
    const int*   ei = (const int*)d_in[1];
    const float* W0 = (const float*)d_in[2];
    const float* b0 = (const float*)d_in[3];
    const float* Ws = (const float*)d_in[4];
    const float* Wc = (const float*)d_in[5];
    const float* bc = (const float*)d_in[6];
    const int E = in_sizes[1] / 2;
    const int N = in_sizes[0] / FIN;
    const int L = in_sizes[4] / (HH * HH);

    float* out    = (float*)d_out;
    float* logits = out;
    float* emb    = out + (size_t)N * FOUT;   // [N,256] — h ping buffer (odd layers) + final h
    float* soft   = emb + (size_t)N * HH;
    float* hard   = soft + (size_t)N * FOUT;

    char* p = (char*)d_ws;
    size_t off = 0;
    auto alloc = [&](size_t bytes) { void* r = p + off; off += (bytes + 255) & ~(size_t)255; return r; };
    int*   cnt         = (int*)alloc((size_t)N * 4);
    int*   row_ptr     = (int*)alloc((size_t)(N + 1) * 4);
    int*   cur         = (int*)alloc((size_t)N * 4);
    int*   partial     = (int*)alloc(4096 * 4);
    float* dinv        = (float*)alloc((size_t)N * 4);
    int*   src_sorted  = (int*)alloc((size_t)E * 4);
    float* norm_sorted = (float*)alloc((size_t)E * 4);
    float* X0          = (float*)alloc((size_t)N * HH * 4);
    float* hA          = (float*)alloc((size_t)N * HH * 4);   // h ping buffer (even layers)
    short* W0hi        = (short*)alloc((size_t)FIN * HH * 2);
    short* W0lo        = (short*)alloc((size_t)FIN * HH * 2);
    short* Wshi        = (short*)alloc((size_t)L * HH * HH * 2);
    short* Wslo        = (short*)alloc((size_t)L * HH * HH * 2);

    const int* srcp = ei;
    const int* dstp = ei + E;

    hipMemsetAsync(cnt, 0, (size_t)N * 4, stream);
    k_count<<<(E + 255) / 256, 256, 0, stream>>>(dstp, cnt, E);
    const int nb = (N + 1023) / 1024;
    k_block_sums<<<nb, 256, 0, stream>>>(cnt, partial, N);
    k_scan_partials<<<1, 64, 0, stream>>>(partial, nb, row_ptr, N);
    k_write_rowptr<<<nb, 256, 0, stream>>>(cnt, partial, row_ptr, cur, N);
    k_dinv<<<(N + 255) / 256, 256, 0, stream>>>(cnt, dinv, N);
    k_scatter<<<(E + 255) / 256, 256, 0, stream>>>(srcp, dstp, dinv, cur, src_sorted, norm_sorted, E);

    k_wprep<<<(FIN * HH / 8 + 255) / 256, 256, 0, stream>>>(W0, W0hi, W0lo, FIN);
    for (int i = 0; i < L; i++)
        k_wprep<<<(HH * HH / 8 + 255) / 256, 256, 0, stream>>>(
            Ws + (size_t)i * HH * HH, Wshi + (size_t)i * HH * HH, Wslo + (size_t)i * HH * HH, HH);

    const int nblk = (N + 63) / 64;
    k_gemm0<<<nblk, 256, 0, stream>>>(x, W0hi, W0lo, b0, X0, N);

    const float* hsrc = X0;
    for (int i = 0; i < L; i++) {
        float beta = (float)log(0.5 / (i + 1) + 1.0);
        float* hdst = (i & 1) ? emb : hA;
        if (i == L - 1) hdst = emb;   // final h lands in the output embedding region
        k_layer<<<nblk, 256, 0, stream>>>(hsrc, X0, row_ptr, src_sorted, norm_sorted, dinv,
                                          Wshi + (size_t)i * HH * HH, Wslo + (size_t)i * HH * HH,
                                          hdst, N, beta);
        hsrc = hdst;
    }
    k_final<<<(N + 3) / 4, 256, 0, stream>>>(emb, Wc, bc, logits, soft, hard);
}